// Round 12
// baseline (237.391 us; speedup 1.0000x reference)
//
#include <hip/hip_runtime.h>
#include <math.h>

#define NN 40000
#define NNP 40192              // NN padded (multiple of 128) for MFMA GEMM
#define NE 500000
#define NEF (NN + NE)
#define NB 512
#define NEG 0.2f
#define NBLK_C 157             // cdiv(NN,256)

static inline int cdiv(int a, int b) { return (a + b - 1) / b; }

typedef __attribute__((ext_vector_type(8))) short short8;
typedef __attribute__((ext_vector_type(4))) short short4v;
typedef __attribute__((ext_vector_type(4))) float f32x4;
typedef __attribute__((ext_vector_type(2))) _Float16 half2v;

__device__ __forceinline__ unsigned short f2bf(float f) {
  unsigned u = __float_as_uint(f);
  unsigned r = (u + 0x7fffu + ((u >> 16) & 1u)) >> 16;
  return (unsigned short)r;
}
__device__ __forceinline__ float bf2f(unsigned short h) {
  return __uint_as_float((unsigned)h << 16);
}
__device__ __forceinline__ float lrelu(float v) {
  return fmaxf(v, NEG * v);   // NEG in (0,1): max(v, 0.2v) == leaky_relu(v)
}
// sum over each aligned 8-lane group, DPP only:
__device__ __forceinline__ float red8(float p) {
  p += __uint_as_float((unsigned)__builtin_amdgcn_mov_dpp((int)__float_as_uint(p), 0xB1, 0xF, 0xF, true));
  p += __uint_as_float((unsigned)__builtin_amdgcn_mov_dpp((int)__float_as_uint(p), 0x4E, 0xF, 0xF, true));
  p += __uint_as_float((unsigned)__builtin_amdgcn_mov_dpp((int)__float_as_uint(p), 0x141, 0xF, 0xF, true));
  return p;
}

// ---------- self-loop attr prep ----------
__global__ void k_deg(const int* __restrict__ ei, const float* __restrict__ ea,
                      int* __restrict__ degi, float* __restrict__ esum) {
  int e = blockIdx.x * 256 + threadIdx.x;
  if (e < NE) {
    int d = ei[NE + e];
    atomicAdd(degi + d, 1);
    atomicAdd(esum + d, ea[e]);
  }
}

// scan1 + lpa finalize + graph-boundary detection (merged; same i<NN grid)
__global__ void k_scanA(const int* __restrict__ degi, int* __restrict__ pre,
                        int* __restrict__ bsum, float* __restrict__ lpa,
                        const int* __restrict__ bat, int* __restrict__ gstart) {
  __shared__ int sh[256];
  int t = threadIdx.x, i = blockIdx.x * 256 + t;
  int dg = i < NN ? degi[i] : -1;
  sh[t] = i < NN ? dg + 1 : 0;   // +1 self loop
  if (i < NN) {
    lpa[i] = dg > 0 ? lpa[i] / (float)dg : 0.f;
    int b = bat[i];
    int bp = i > 0 ? bat[i - 1] : -1;
    for (int g = bp + 1; g <= b; g++) gstart[g] = i;
    if (i == NN - 1)
      for (int g = b + 1; g <= NB; g++) gstart[g] = NN;
  }
  __syncthreads();
  for (int st = 1; st < 256; st <<= 1) {
    int a = t >= st ? sh[t - st] : 0;
    __syncthreads();
    sh[t] += a;
    __syncthreads();
  }
  if (i < NN) pre[i] = sh[t];
  if (t == 255) bsum[blockIdx.x] = sh[255];
}

// scan3 with block-sum prefix computed locally (NBLK_C <= 256)
__global__ void k_scan3(const int* __restrict__ pre, const int* __restrict__ bsum,
                        int* __restrict__ rowptr) {
  __shared__ int sh[256];
  int t = threadIdx.x;
  sh[t] = t < NBLK_C ? bsum[t] : 0;
  __syncthreads();
  for (int st = 1; st < 256; st <<= 1) {
    int a = t >= st ? sh[t - st] : 0;
    __syncthreads();
    sh[t] += a;
    __syncthreads();
  }
  int i = blockIdx.x * 256 + t;
  if (i < NN) {
    int off = blockIdx.x > 0 ? sh[blockIdx.x - 1] : 0;
    rowptr[i + 1] = pre[i] + off;
    if (i == 0) rowptr[0] = 0;
  }
}

// fill CSR with packed {src, eav} records (one 8B store per edge)
__global__ void k_fill(const int* __restrict__ ei, const float* __restrict__ ea,
                       const float* __restrict__ lpa, const int* __restrict__ rowptr,
                       int* __restrict__ fillc, int2* __restrict__ cedge) {
  int e = blockIdx.x * 256 + threadIdx.x;
  if (e >= NEF) return;
  int s, d;
  float v;
  if (e < NE) { s = ei[e]; d = ei[NE + e]; v = ea[e]; }
  else        { s = e - NE; d = s; v = lpa[s]; }
  int pos = atomicAdd(fillc + d, 1);
  int idx = rowptr[d] + pos;
  cedge[idx] = make_int2(s, __float_as_int(v));
}

// ---------- layer 1 fully fused, strength-reduced; 2-edge-deep prefetch ----------
__global__ __launch_bounds__(256) void k_gat1(const int* __restrict__ rowptr,
                                              const int2* __restrict__ cedge,
                                              const float* __restrict__ xx,
                                              const float* __restrict__ w0,
                                              const float* __restrict__ b0,
                                              const float* __restrict__ wl,
                                              const float* __restrict__ wr,
                                              const float* __restrict__ we,
                                              const float* __restrict__ att,
                                              const float* __restrict__ bias,
                                              short* __restrict__ ah,
                                              short* __restrict__ al) {
  const int lane = threadIdx.x & 63;
  const int node = __builtin_amdgcn_readfirstlane(blockIdx.x * 4 + (threadIdx.x >> 6));
  const int j0 = lane * 4;
  if (node >= NN) {  // zero GEMM pad rows (node < NNP by grid construction)
    short4v z = {0, 0, 0, 0};
    *(short4v*)(ah + (size_t)node * 256 + j0) = z;
    *(short4v*)(al + (size_t)node * 256 + j0) = z;
    return;
  }

  float4 wev = *(const float4*)(we + j0);
  float4 attv = *(const float4*)(att + j0);
  float w0s[4] = {w0[0], w0[1], w0[2], w0[3]};
  float b0s[4] = {b0[0], b0[1], b0[2], b0[3]};
  float u[4] = {0.f, 0.f, 0.f, 0.f}, v[4] = {0.f, 0.f, 0.f, 0.f};
#pragma unroll
  for (int j = 0; j < 4; j++) {
    float4 t = *(const float4*)(wl + j * 256 + j0);
    float tt[4] = {t.x, t.y, t.z, t.w};
#pragma unroll
    for (int c = 0; c < 4; c++) {
      u[c] = fmaf(w0s[j], tt[c], u[c]);
      v[c] = fmaf(b0s[j], tt[c], v[c]);
    }
  }
  float4 wl4 = *(const float4*)(wl + 4 * 256 + j0);
  float4 wl5 = *(const float4*)(wl + 5 * 256 + j0);
  float4 wl6 = *(const float4*)(wl + 6 * 256 + j0);

  float xrr[4] = {0.f, 0.f, 0.f, 0.f};
  {
    float4 xv = *(const float4*)(xx + (size_t)node * 4);
    float hn[7] = {fmaf(xv.x, w0s[0], b0s[0]), fmaf(xv.x, w0s[1], b0s[1]),
                   fmaf(xv.x, w0s[2], b0s[2]), fmaf(xv.x, w0s[3], b0s[3]),
                   xv.y, xv.z, xv.w};
#pragma unroll
    for (int k = 0; k < 7; k++) {
      float4 t = *(const float4*)(wr + k * 256 + j0);
      xrr[0] = fmaf(hn[k], t.x, xrr[0]);
      xrr[1] = fmaf(hn[k], t.y, xrr[1]);
      xrr[2] = fmaf(hn[k], t.z, xrr[2]);
      xrr[3] = fmaf(hn[k], t.w, xrr[3]);
    }
  }

  float m = -INFINITY, den = 0.f;
  float acc[4] = {0.f, 0.f, 0.f, 0.f};
  const int kb = rowptr[node], ke = rowptr[node + 1];

#define G1_EDGE(XS, EAV)                                                        \
  {                                                                             \
    float xls[4];                                                               \
    _Pragma("unroll")                                                           \
    for (int c = 0; c < 4; c++) xls[c] = fmaf((XS).x, u[c], v[c]);              \
    xls[0] = fmaf((XS).y, wl4.x, xls[0]); xls[1] = fmaf((XS).y, wl4.y, xls[1]); \
    xls[2] = fmaf((XS).y, wl4.z, xls[2]); xls[3] = fmaf((XS).y, wl4.w, xls[3]); \
    xls[0] = fmaf((XS).z, wl5.x, xls[0]); xls[1] = fmaf((XS).z, wl5.y, xls[1]); \
    xls[2] = fmaf((XS).z, wl5.z, xls[2]); xls[3] = fmaf((XS).z, wl5.w, xls[3]); \
    xls[0] = fmaf((XS).w, wl6.x, xls[0]); xls[1] = fmaf((XS).w, wl6.y, xls[1]); \
    xls[2] = fmaf((XS).w, wl6.z, xls[2]); xls[3] = fmaf((XS).w, wl6.w, xls[3]); \
    float p = 0.f;                                                              \
    p = fmaf(lrelu(xls[0] + fmaf((EAV), wev.x, xrr[0])), attv.x, p);            \
    p = fmaf(lrelu(xls[1] + fmaf((EAV), wev.y, xrr[1])), attv.y, p);            \
    p = fmaf(lrelu(xls[2] + fmaf((EAV), wev.z, xrr[2])), attv.z, p);            \
    p = fmaf(lrelu(xls[3] + fmaf((EAV), wev.w, xrr[3])), attv.w, p);            \
    p = red8(p);                                                                \
    if (!__all(p <= m + 8.f)) {                                                 \
      float mn = fmaxf(m, p);                                                   \
      float sc = __expf(m - mn);                                                \
      den *= sc;                                                                \
      _Pragma("unroll")                                                         \
      for (int c = 0; c < 4; c++) acc[c] *= sc;                                 \
      m = mn;                                                                   \
    }                                                                           \
    float ex = __expf(p - m);                                                   \
    den += ex;                                                                  \
    _Pragma("unroll")                                                           \
    for (int c = 0; c < 4; c++) acc[c] = fmaf(ex, xls[c], acc[c]);              \
  }

  int i1 = kb + 1 < ke ? kb + 1 : ke - 1;
  int2 edA = cedge[kb], edB = cedge[i1];
  float4 xA = *(const float4*)(xx + (size_t)edA.x * 4);
  float4 xB = *(const float4*)(xx + (size_t)edB.x * 4);
  for (int k = kb; k < ke; k += 2) {
    const int i2 = k + 2 < ke ? k + 2 : ke - 1;
    const int i3 = k + 3 < ke ? k + 3 : ke - 1;
    const int2 edC = cedge[i2], edD = cedge[i3];
    const float4 xC = *(const float4*)(xx + (size_t)edC.x * 4);
    const float4 xD = *(const float4*)(xx + (size_t)edD.x * 4);
    G1_EDGE(xA, __int_as_float(edA.y));
    if (k + 1 < ke) {          // wave-uniform guard
      G1_EDGE(xB, __int_as_float(edB.y));
    }
    xA = xC; edA = edC; xB = xD; edB = edD;
  }
#undef G1_EDGE

  float rd = 1.f / den;
  float4 bv = *(const float4*)(bias + j0);
  float bb[4] = {bv.x, bv.y, bv.z, bv.w};
  short hi[4], lo[4];
#pragma unroll
  for (int c = 0; c < 4; c++) {
    float hv = tanhf(fmaf(acc[c], rd, bb[c]));
    unsigned short hb = f2bf(hv);
    hi[c] = (short)hb;
    lo[c] = (short)f2bf(hv - bf2f(hb));
  }
  *(short4v*)(ah + (size_t)node * 256 + j0) = *(short4v*)hi;
  *(short4v*)(al + (size_t)node * 256 + j0) = *(short4v*)lo;
}

// ---------- W2 split + W3 transpose (one kernel, 264 blocks) ----------
__global__ void k_wsplit(const float* __restrict__ wl, const float* __restrict__ wr,
                         short* __restrict__ bh, short* __restrict__ bl,
                         const float* __restrict__ wl3, const float* __restrict__ wr3,
                         float* __restrict__ w3t) {
  int id = blockIdx.x * 256 + threadIdx.x;
  if (id < 65536) {
    int n = id >> 8, k = id & 255;
    float w = n < 128 ? wl[k * 128 + n] : wr[k * 128 + n - 128];
    unsigned short hb = f2bf(w);
    bh[n * 256 + k] = (short)hb;
    bl[n * 256 + k] = (short)f2bf(w - bf2f(hb));
  } else if (id < 65536 + 2048) {
    int t = id - 65536;               // 0..2047
    int j = t >> 7, k = t & 127;      // j in [0,16), k in [0,128)
    w3t[j * 128 + k] = j < 8 ? wl3[k * 8 + j] : wr3[k * 8 + (j - 8)];
  }
}

// layer-2 GEMM (known-good structure) + XCD-chunked swizzle:
// BM=128 x BN=64, BK=32; single K-sweep, acc += Ah·Bh + Ah·Bl + Al·Bh.
__global__ __launch_bounds__(256) void k_gemm2(const short* __restrict__ ah,
                                               const short* __restrict__ al,
                                               const short* __restrict__ bh,
                                               const short* __restrict__ bl,
                                               _Float16* __restrict__ xlh,
                                               float* __restrict__ xr) {
  __shared__ short sAh[128 * 40];
  __shared__ short sAl[128 * 40];
  __shared__ short sBh[64 * 40];
  __shared__ short sBl[64 * 40];
  const int tid = threadIdx.x;
  // XCD-chunked swizzle: nwg = (NNP/128)*4 = 1256 = 8*157.
  // Same-bm blocks land on the same XCD -> A-tile L2 reuse across 4 bn.
  const int wgid = (blockIdx.x & 7) * ((NNP / 128) * 4 / 8) + (blockIdx.x >> 3);
  const int bm = wgid >> 2, bn = wgid & 3;
  const int wid = tid >> 6, lane = tid & 63;
  const int wr = wid >> 1, wc = wid & 1;
  const int l15 = lane & 15, lhi = lane >> 4;
  const int srow = tid >> 2;
  const int kq = (tid & 3) * 8;
  f32x4 acc[4][2];
#pragma unroll
  for (int a = 0; a < 4; a++)
#pragma unroll
    for (int b = 0; b < 2; b++) acc[a][b] = (f32x4)(0.f);

#pragma unroll 1
  for (int st = 0; st < 8; st++) {
    const int k0 = st * 32;
    const long aoff0 = (long)(bm * 128 + srow) * 256 + k0 + kq;
    const long aoff1 = aoff0 + 64 * 256;
    const long boff = (long)(bn * 64 + srow) * 256 + k0 + kq;
    short8 vah0 = *(const short8*)(ah + aoff0);
    short8 vah1 = *(const short8*)(ah + aoff1);
    short8 val0 = *(const short8*)(al + aoff0);
    short8 val1 = *(const short8*)(al + aoff1);
    short8 vbh  = *(const short8*)(bh + boff);
    short8 vbl  = *(const short8*)(bl + boff);
    __syncthreads();
    *(short8*)&sAh[srow * 40 + kq] = vah0;
    *(short8*)&sAh[(64 + srow) * 40 + kq] = vah1;
    *(short8*)&sAl[srow * 40 + kq] = val0;
    *(short8*)&sAl[(64 + srow) * 40 + kq] = val1;
    *(short8*)&sBh[srow * 40 + kq] = vbh;
    *(short8*)&sBl[srow * 40 + kq] = vbl;
    __syncthreads();
    short8 bfh[2], bfl[2];
#pragma unroll
    for (int fn = 0; fn < 2; fn++) {
      bfh[fn] = *(const short8*)&sBh[(wc * 32 + fn * 16 + l15) * 40 + lhi * 8];
      bfl[fn] = *(const short8*)&sBl[(wc * 32 + fn * 16 + l15) * 40 + lhi * 8];
    }
#pragma unroll
    for (int fm = 0; fm < 4; fm++) {
      short8 afh = *(const short8*)&sAh[(wr * 64 + fm * 16 + l15) * 40 + lhi * 8];
      short8 afl = *(const short8*)&sAl[(wr * 64 + fm * 16 + l15) * 40 + lhi * 8];
      acc[fm][0] = __builtin_amdgcn_mfma_f32_16x16x32_bf16(afh, bfh[0], acc[fm][0], 0, 0, 0);
      acc[fm][1] = __builtin_amdgcn_mfma_f32_16x16x32_bf16(afh, bfh[1], acc[fm][1], 0, 0, 0);
      acc[fm][0] = __builtin_amdgcn_mfma_f32_16x16x32_bf16(afh, bfl[0], acc[fm][0], 0, 0, 0);
      acc[fm][1] = __builtin_amdgcn_mfma_f32_16x16x32_bf16(afh, bfl[1], acc[fm][1], 0, 0, 0);
      acc[fm][0] = __builtin_amdgcn_mfma_f32_16x16x32_bf16(afl, bfh[0], acc[fm][0], 0, 0, 0);
      acc[fm][1] = __builtin_amdgcn_mfma_f32_16x16x32_bf16(afl, bfh[1], acc[fm][1], 0, 0, 0);
    }
  }
#pragma unroll
  for (int fm = 0; fm < 4; fm++)
#pragma unroll
    for (int fn = 0; fn < 2; fn++) {
      int col = bn * 64 + wc * 32 + fn * 16 + l15;
#pragma unroll
      for (int j = 0; j < 4; j++) {
        int row = bm * 128 + wr * 64 + fm * 16 + lhi * 4 + j;
        if (col < 128) xlh[(long)row * 128 + col] = (_Float16)acc[fm][fn][j];
        else           xr[(long)row * 128 + col - 128] = acc[fm][fn][j];
      }
    }
}

// ---------- layer 2 gather + fused layer-3 transform ----------
// Each wave owns one node: edge loop -> h2 row in LDS (wave-local) ->
// 16 layer-3 outputs via 4-lane x 32-k split + shfl reduce. No barrier needed.
__global__ __launch_bounds__(256) void k_gat2(const int* __restrict__ rowptr,
                                              const int2* __restrict__ cedge,
                                              const _Float16* __restrict__ xlh,
                                              const float* __restrict__ xr,
                                              const float* __restrict__ we,
                                              const float* __restrict__ att,
                                              const float* __restrict__ bias,
                                              const float* __restrict__ w3t,
                                              float* __restrict__ xl3,
                                              float* __restrict__ xr3) {
  __shared__ float h2s[4][128];
  const int lane = threadIdx.x & 63;
  const int w = threadIdx.x >> 6;
  const int node = __builtin_amdgcn_readfirstlane(blockIdx.x * 4 + w);
  if (node >= NN) return;
  const int j0 = lane * 2;
  float2 xrr = *(const float2*)(xr + (long)node * 128 + j0);
  float2 wev = *(const float2*)(we + j0);
  float2 attv = *(const float2*)(att + j0);
  float m = -INFINITY, den = 0.f, acc0 = 0.f, acc1 = 0.f;
  const int kb = rowptr[node], ke = rowptr[node + 1];

#define G2_EDGE(AV, EAV)                                                  \
  {                                                                       \
    float av0 = (float)(AV).x, av1 = (float)(AV).y;                       \
    float v0 = lrelu(av0 + fmaf((EAV), wev.x, xrr.x));                    \
    float v1 = lrelu(av1 + fmaf((EAV), wev.y, xrr.y));                    \
    float p = red8(fmaf(v0, attv.x, v1 * attv.y));                        \
    if (!__all(p <= m + 8.f)) {                                           \
      float mn = fmaxf(m, p);                                             \
      float sc = __expf(m - mn);                                          \
      den *= sc;                                                          \
      acc0 *= sc;                                                         \
      acc1 *= sc;                                                         \
      m = mn;                                                             \
    }                                                                     \
    float ex = __expf(p - m);                                             \
    den += ex;                                                            \
    acc0 = fmaf(ex, av0, acc0);                                           \
    acc1 = fmaf(ex, av1, acc1);                                           \
  }

  int i1 = kb + 1 < ke ? kb + 1 : ke - 1;
  int2 edA = cedge[kb], edB = cedge[i1];
  half2v aA = *(const half2v*)(xlh + (long)edA.x * 128 + j0);
  half2v aB = *(const half2v*)(xlh + (long)edB.x * 128 + j0);
  for (int k = kb; k < ke; k += 2) {
    const int i2 = k + 2 < ke ? k + 2 : ke - 1;
    const int i3 = k + 3 < ke ? k + 3 : ke - 1;
    const int2 edC = cedge[i2], edD = cedge[i3];
    const half2v aC = *(const half2v*)(xlh + (long)edC.x * 128 + j0);
    const half2v aD = *(const half2v*)(xlh + (long)edD.x * 128 + j0);
    G2_EDGE(aA, __int_as_float(edA.y));
    if (k + 1 < ke) {
      G2_EDGE(aB, __int_as_float(edB.y));
    }
    aA = aC; edA = edC; aB = aD; edB = edD;
  }
#undef G2_EDGE

  float rd = 1.f / den;
  float t0 = tanhf(fmaf(acc0, rd, bias[j0]));
  float t1 = tanhf(fmaf(acc1, rd, bias[j0 + 1]));
  float2 tw = {t0, t1};
  *(float2*)&h2s[w][j0] = tw;          // wave-local LDS (same wave reads below)

  // layer-3 transform: output j computed by lanes {j, j+16, j+32, j+48}
  const int j = lane & 15, q = lane >> 4;
  const float* hp = &h2s[w][q * 32];
  const float* wp = w3t + j * 128 + q * 32;
  float a3 = 0.f;
#pragma unroll
  for (int i = 0; i < 8; i++) {
    float4 hv = *(const float4*)(hp + i * 4);
    float4 wv = *(const float4*)(wp + i * 4);
    a3 = fmaf(hv.x, wv.x, a3);
    a3 = fmaf(hv.y, wv.y, a3);
    a3 = fmaf(hv.z, wv.z, a3);
    a3 = fmaf(hv.w, wv.w, a3);
  }
  a3 += __shfl_xor(a3, 16);
  a3 += __shfl_xor(a3, 32);
  if (lane < 16) {
    if (j < 8) xl3[node * 8 + j] = a3;
    else       xr3[node * 8 + (j - 8)] = a3;
  }
}

// ---------- layer 3 gather: O=8, H=1, 8-lane group per node; 2-deep prefetch ----------
__global__ __launch_bounds__(256) void k_gat3(const int* __restrict__ rowptr,
                                              const int2* __restrict__ cedge,
                                              const float* __restrict__ xl,
                                              const float* __restrict__ xr,
                                              const float* __restrict__ we,
                                              const float* __restrict__ att,
                                              const float* __restrict__ bias,
                                              float* __restrict__ hout) {
  const int lane = threadIdx.x & 7;
  const int node = blockIdx.x * 32 + (threadIdx.x >> 3);
  if (node >= NN) return;
  const float xrr = xr[node * 8 + lane];
  const float wev = we[lane];
  const float attv = att[lane];
  float m = -INFINITY, den = 0.f, acc = 0.f;
  const int kb = rowptr[node], ke = rowptr[node + 1];

#define G3_EDGE(AV, EAV)                                      \
  {                                                           \
    float v = lrelu((AV) + fmaf((EAV), wev, xrr));            \
    float p = red8(v * attv);                                 \
    if (p > m + 8.f) {                                        \
      float mn = fmaxf(m, p);                                 \
      float sc = __expf(m - mn);                              \
      den *= sc;                                              \
      acc *= sc;                                              \
      m = mn;                                                 \
    }                                                         \
    float ex = __expf(p - m);                                 \
    den += ex;                                                \
    acc = fmaf(ex, (AV), acc);                                \
  }

  int i1 = kb + 1 < ke ? kb + 1 : ke - 1;
  int2 edA = cedge[kb], edB = cedge[i1];
  float aA = xl[edA.x * 8 + lane];
  float aB = xl[edB.x * 8 + lane];
  for (int k = kb; k < ke; k += 2) {
    const int i2 = k + 2 < ke ? k + 2 : ke - 1;
    const int i3 = k + 3 < ke ? k + 3 : ke - 1;
    const int2 edC = cedge[i2], edD = cedge[i3];
    const float aC = xl[edC.x * 8 + lane];
    const float aD = xl[edD.x * 8 + lane];
    G3_EDGE(aA, __int_as_float(edA.y));
    if (k + 1 < ke) {
      G3_EDGE(aB, __int_as_float(edB.y));
    }
    aA = aC; edA = edC; aB = aD; edB = edD;
  }
#undef G3_EDGE

  hout[node * 8 + lane] = tanhf(acc / den + bias[lane]);
}

// one wave per graph: segmented mean-pool + head, no atomics.
__global__ __launch_bounds__(256) void k_poolG(const int* __restrict__ gstart,
                                               const float* __restrict__ h3,
                                               const float* __restrict__ w4,
                                               const float* __restrict__ b4,
                                               float* __restrict__ out) {
  const int lane = threadIdx.x & 63;
  const int g = blockIdx.x * 4 + (threadIdx.x >> 6);
  if (g >= NB) return;
  const int kb = gstart[g], ke = gstart[g + 1];
  const int ch = lane & 7, no = lane >> 3;
  float acc = 0.f;
  for (int n = kb + no; n < ke; n += 8)
    acc += h3[(size_t)n * 8 + ch];
  acc += __shfl_xor(acc, 8);
  acc += __shfl_xor(acc, 16);
  acc += __shfl_xor(acc, 32);
  float cnt = fmaxf((float)(ke - kb), 1.f);
  float yv = (acc / cnt) * w4[ch];
  yv = red8(yv);
  if (lane == 0) out[g] = yv + b4[0];
}

extern "C" void kernel_launch(void* const* d_in, const int* in_sizes, int n_in,
                              void* d_out, int out_size, void* d_ws, size_t ws_size,
                              hipStream_t stream) {
  const float* x   = (const float*)d_in[0];
  const int*   ei  = (const int*)d_in[1];
  const float* ea  = (const float*)d_in[2];
  const int*   bat = (const int*)d_in[3];
  const float* w0  = (const float*)d_in[4];
  const float* b0  = (const float*)d_in[5];
  const float* wl1 = (const float*)d_in[6];
  const float* wr1 = (const float*)d_in[7];
  const float* we1 = (const float*)d_in[8];
  const float* at1 = (const float*)d_in[9];
  const float* b1  = (const float*)d_in[10];
  const float* wl2 = (const float*)d_in[11];
  const float* wr2 = (const float*)d_in[12];
  const float* we2 = (const float*)d_in[13];
  const float* at2 = (const float*)d_in[14];
  const float* b2  = (const float*)d_in[15];
  const float* wl3 = (const float*)d_in[16];
  const float* wr3 = (const float*)d_in[17];
  const float* we3 = (const float*)d_in[18];
  const float* at3 = (const float*)d_in[19];
  const float* b3  = (const float*)d_in[20];
  const float* w4  = (const float*)d_in[21];
  const float* b4  = (const float*)d_in[22];
  float* out = (float*)d_out;

  char* W = (char*)d_ws;
  size_t o = 0;
  auto alloc = [&](size_t bytes) { void* p = W + o; o += (bytes + 255) & ~(size_t)255; return p; };
  int*      degi   = (int*)alloc(NN * 4);   // degi/fillc/lpa contiguous (one memset)
  int*      fillc  = (int*)alloc(NN * 4);
  float*    lpa    = (float*)alloc(NN * 4);
  int*      rowptr = (int*)alloc((NN + 1) * 4);
  int*      pre    = (int*)alloc(NN * 4);
  int*      bsum   = (int*)alloc(256 * 4);
  int*      gstart = (int*)alloc((NB + 1) * 4);
  int2*     cedge  = (int2*)alloc((size_t)NEF * 8);
  short*    Ah     = (short*)alloc((size_t)NNP * 256 * 2);
  short*    Al     = (short*)alloc((size_t)NNP * 256 * 2);
  short*    Bh     = (short*)alloc((size_t)256 * 256 * 2);
  short*    Bl     = (short*)alloc((size_t)256 * 256 * 2);
  float*    W3t    = (float*)alloc(16 * 128 * 4);
  _Float16* Xlh2   = (_Float16*)alloc((size_t)NNP * 128 * 2);
  float*    Xr2    = (float*)alloc((size_t)NNP * 128 * 4);
  float*    Xl3    = (float*)alloc((size_t)NN * 8 * 4);
  float*    Xr3    = (float*)alloc((size_t)NN * 8 * 4);
  float*    H3     = (float*)alloc((size_t)NN * 8 * 4);
  (void)ws_size; (void)in_sizes; (void)n_in; (void)out_size;

  const int NBLK = cdiv(NN, 256);  // == NBLK_C

  // ---- CSR build (+ graph bounds merged into scanA) ----
  hipMemsetAsync(degi, 0, 3 * NN * 4, stream);  // degi + fillc + lpa
  k_deg<<<cdiv(NE, 256), 256, 0, stream>>>(ei, ea, degi, lpa);
  k_scanA<<<NBLK, 256, 0, stream>>>(degi, pre, bsum, lpa, bat, gstart);
  k_scan3<<<NBLK, 256, 0, stream>>>(pre, bsum, rowptr);
  k_fill<<<cdiv(NEF, 256), 256, 0, stream>>>(ei, ea, lpa, rowptr, fillc, cedge);

  // ---- layer 1 (fused transform+gather from raw x; emits bf16 hi/lo h1) ----
  k_gat1<<<NNP / 4, 256, 0, stream>>>(rowptr, cedge, x, w0, b0, wl1, wr1, we1, at1, b1, Ah, Al);

  // ---- layer 2: MFMA GEMM (XCD-swizzled) + fused gather/transform ----
  k_wsplit<<<264, 256, 0, stream>>>(wl2, wr2, Bh, Bl, wl3, wr3, W3t);
  k_gemm2<<<(NNP / 128) * 4, 256, 0, stream>>>(Ah, Al, Bh, Bl, Xlh2, Xr2);
  k_gat2<<<cdiv(NN, 4), 256, 0, stream>>>(rowptr, cedge, Xlh2, Xr2, we2, at2, b2, W3t, Xl3, Xr3);

  // ---- layer 3 gather ----
  k_gat3<<<cdiv(NN, 32), 256, 0, stream>>>(rowptr, cedge, Xl3, Xr3, we3, at3, b3, H3);

  // ---- pooling + head (segmented, no atomics) ----
  k_poolG<<<cdiv(NB, 4), 256, 0, stream>>>(gstart, H3, w4, b4, out);
}

// Round 13
// 233.627 us; speedup vs baseline: 1.0161x; 1.0161x over previous
//
#include <hip/hip_runtime.h>
#include <math.h>

#define NN 40000
#define NNP 40192              // NN padded (multiple of 128) for MFMA GEMM
#define NE 500000
#define NEF (NN + NE)
#define NB 512
#define NEG 0.2f
#define NBLK_C 157             // cdiv(NN,256)

static inline int cdiv(int a, int b) { return (a + b - 1) / b; }

typedef __attribute__((ext_vector_type(8))) short short8;
typedef __attribute__((ext_vector_type(4))) short short4v;
typedef __attribute__((ext_vector_type(4))) float f32x4;
typedef __attribute__((ext_vector_type(2))) _Float16 half2v;

__device__ __forceinline__ unsigned short f2bf(float f) {
  unsigned u = __float_as_uint(f);
  unsigned r = (u + 0x7fffu + ((u >> 16) & 1u)) >> 16;
  return (unsigned short)r;
}
__device__ __forceinline__ float bf2f(unsigned short h) {
  return __uint_as_float((unsigned)h << 16);
}
__device__ __forceinline__ float lrelu(float v) {
  return fmaxf(v, NEG * v);   // NEG in (0,1): max(v, 0.2v) == leaky_relu(v)
}
// sum over each aligned 8-lane group, DPP only:
__device__ __forceinline__ float red8(float p) {
  p += __uint_as_float((unsigned)__builtin_amdgcn_mov_dpp((int)__float_as_uint(p), 0xB1, 0xF, 0xF, true));
  p += __uint_as_float((unsigned)__builtin_amdgcn_mov_dpp((int)__float_as_uint(p), 0x4E, 0xF, 0xF, true));
  p += __uint_as_float((unsigned)__builtin_amdgcn_mov_dpp((int)__float_as_uint(p), 0x141, 0xF, 0xF, true));
  return p;
}

// ---------- self-loop attr prep ----------
__global__ void k_deg(const int* __restrict__ ei, const float* __restrict__ ea,
                      int* __restrict__ degi, float* __restrict__ esum) {
  int e = blockIdx.x * 256 + threadIdx.x;
  if (e < NE) {
    int d = ei[NE + e];
    atomicAdd(degi + d, 1);
    atomicAdd(esum + d, ea[e]);
  }
}

// scan1 + lpa finalize + graph-boundary detection (merged; same i<NN grid)
__global__ void k_scanA(const int* __restrict__ degi, int* __restrict__ pre,
                        int* __restrict__ bsum, float* __restrict__ lpa,
                        const int* __restrict__ bat, int* __restrict__ gstart) {
  __shared__ int sh[256];
  int t = threadIdx.x, i = blockIdx.x * 256 + t;
  int dg = i < NN ? degi[i] : -1;
  sh[t] = i < NN ? dg + 1 : 0;   // +1 self loop
  if (i < NN) {
    lpa[i] = dg > 0 ? lpa[i] / (float)dg : 0.f;
    int b = bat[i];
    int bp = i > 0 ? bat[i - 1] : -1;
    for (int g = bp + 1; g <= b; g++) gstart[g] = i;
    if (i == NN - 1)
      for (int g = b + 1; g <= NB; g++) gstart[g] = NN;
  }
  __syncthreads();
  for (int st = 1; st < 256; st <<= 1) {
    int a = t >= st ? sh[t - st] : 0;
    __syncthreads();
    sh[t] += a;
    __syncthreads();
  }
  if (i < NN) pre[i] = sh[t];
  if (t == 255) bsum[blockIdx.x] = sh[255];
}

// scan3 with block-sum prefix computed locally (NBLK_C <= 256)
__global__ void k_scan3(const int* __restrict__ pre, const int* __restrict__ bsum,
                        int* __restrict__ rowptr) {
  __shared__ int sh[256];
  int t = threadIdx.x;
  sh[t] = t < NBLK_C ? bsum[t] : 0;
  __syncthreads();
  for (int st = 1; st < 256; st <<= 1) {
    int a = t >= st ? sh[t - st] : 0;
    __syncthreads();
    sh[t] += a;
    __syncthreads();
  }
  int i = blockIdx.x * 256 + t;
  if (i < NN) {
    int off = blockIdx.x > 0 ? sh[blockIdx.x - 1] : 0;
    rowptr[i + 1] = pre[i] + off;
    if (i == 0) rowptr[0] = 0;
  }
}

// fill CSR with packed {src, eav} records (one 8B store per edge)
__global__ void k_fill(const int* __restrict__ ei, const float* __restrict__ ea,
                       const float* __restrict__ lpa, const int* __restrict__ rowptr,
                       int* __restrict__ fillc, int2* __restrict__ cedge) {
  int e = blockIdx.x * 256 + threadIdx.x;
  if (e >= NEF) return;
  int s, d;
  float v;
  if (e < NE) { s = ei[e]; d = ei[NE + e]; v = ea[e]; }
  else        { s = e - NE; d = s; v = lpa[s]; }
  int pos = atomicAdd(fillc + d, 1);
  int idx = rowptr[d] + pos;
  cedge[idx] = make_int2(s, __float_as_int(v));
}

// ---------- layer 1 fully fused, strength-reduced; 2-edge-deep prefetch ----------
__global__ __launch_bounds__(256) void k_gat1(const int* __restrict__ rowptr,
                                              const int2* __restrict__ cedge,
                                              const float* __restrict__ xx,
                                              const float* __restrict__ w0,
                                              const float* __restrict__ b0,
                                              const float* __restrict__ wl,
                                              const float* __restrict__ wr,
                                              const float* __restrict__ we,
                                              const float* __restrict__ att,
                                              const float* __restrict__ bias,
                                              short* __restrict__ ah,
                                              short* __restrict__ al) {
  const int lane = threadIdx.x & 63;
  const int node = __builtin_amdgcn_readfirstlane(blockIdx.x * 4 + (threadIdx.x >> 6));
  const int j0 = lane * 4;
  if (node >= NN) {  // zero GEMM pad rows (node < NNP by grid construction)
    short4v z = {0, 0, 0, 0};
    *(short4v*)(ah + (size_t)node * 256 + j0) = z;
    *(short4v*)(al + (size_t)node * 256 + j0) = z;
    return;
  }

  float4 wev = *(const float4*)(we + j0);
  float4 attv = *(const float4*)(att + j0);
  float w0s[4] = {w0[0], w0[1], w0[2], w0[3]};
  float b0s[4] = {b0[0], b0[1], b0[2], b0[3]};
  float u[4] = {0.f, 0.f, 0.f, 0.f}, v[4] = {0.f, 0.f, 0.f, 0.f};
#pragma unroll
  for (int j = 0; j < 4; j++) {
    float4 t = *(const float4*)(wl + j * 256 + j0);
    float tt[4] = {t.x, t.y, t.z, t.w};
#pragma unroll
    for (int c = 0; c < 4; c++) {
      u[c] = fmaf(w0s[j], tt[c], u[c]);
      v[c] = fmaf(b0s[j], tt[c], v[c]);
    }
  }
  float4 wl4 = *(const float4*)(wl + 4 * 256 + j0);
  float4 wl5 = *(const float4*)(wl + 5 * 256 + j0);
  float4 wl6 = *(const float4*)(wl + 6 * 256 + j0);

  float xrr[4] = {0.f, 0.f, 0.f, 0.f};
  {
    float4 xv = *(const float4*)(xx + (size_t)node * 4);
    float hn[7] = {fmaf(xv.x, w0s[0], b0s[0]), fmaf(xv.x, w0s[1], b0s[1]),
                   fmaf(xv.x, w0s[2], b0s[2]), fmaf(xv.x, w0s[3], b0s[3]),
                   xv.y, xv.z, xv.w};
#pragma unroll
    for (int k = 0; k < 7; k++) {
      float4 t = *(const float4*)(wr + k * 256 + j0);
      xrr[0] = fmaf(hn[k], t.x, xrr[0]);
      xrr[1] = fmaf(hn[k], t.y, xrr[1]);
      xrr[2] = fmaf(hn[k], t.z, xrr[2]);
      xrr[3] = fmaf(hn[k], t.w, xrr[3]);
    }
  }

  float m = -INFINITY, den = 0.f;
  float acc[4] = {0.f, 0.f, 0.f, 0.f};
  const int kb = rowptr[node], ke = rowptr[node + 1];

#define G1_EDGE(XS, EAV)                                                        \
  {                                                                             \
    float xls[4];                                                               \
    _Pragma("unroll")                                                           \
    for (int c = 0; c < 4; c++) xls[c] = fmaf((XS).x, u[c], v[c]);              \
    xls[0] = fmaf((XS).y, wl4.x, xls[0]); xls[1] = fmaf((XS).y, wl4.y, xls[1]); \
    xls[2] = fmaf((XS).y, wl4.z, xls[2]); xls[3] = fmaf((XS).y, wl4.w, xls[3]); \
    xls[0] = fmaf((XS).z, wl5.x, xls[0]); xls[1] = fmaf((XS).z, wl5.y, xls[1]); \
    xls[2] = fmaf((XS).z, wl5.z, xls[2]); xls[3] = fmaf((XS).z, wl5.w, xls[3]); \
    xls[0] = fmaf((XS).w, wl6.x, xls[0]); xls[1] = fmaf((XS).w, wl6.y, xls[1]); \
    xls[2] = fmaf((XS).w, wl6.z, xls[2]); xls[3] = fmaf((XS).w, wl6.w, xls[3]); \
    float p = 0.f;                                                              \
    p = fmaf(lrelu(xls[0] + fmaf((EAV), wev.x, xrr[0])), attv.x, p);            \
    p = fmaf(lrelu(xls[1] + fmaf((EAV), wev.y, xrr[1])), attv.y, p);            \
    p = fmaf(lrelu(xls[2] + fmaf((EAV), wev.z, xrr[2])), attv.z, p);            \
    p = fmaf(lrelu(xls[3] + fmaf((EAV), wev.w, xrr[3])), attv.w, p);            \
    p = red8(p);                                                                \
    if (!__all(p <= m + 8.f)) {                                                 \
      float mn = fmaxf(m, p);                                                   \
      float sc = __expf(m - mn);                                                \
      den *= sc;                                                                \
      _Pragma("unroll")                                                         \
      for (int c = 0; c < 4; c++) acc[c] *= sc;                                 \
      m = mn;                                                                   \
    }                                                                           \
    float ex = __expf(p - m);                                                   \
    den += ex;                                                                  \
    _Pragma("unroll")                                                           \
    for (int c = 0; c < 4; c++) acc[c] = fmaf(ex, xls[c], acc[c]);              \
  }

  int i1 = kb + 1 < ke ? kb + 1 : ke - 1;
  int2 edA = cedge[kb], edB = cedge[i1];
  float4 xA = *(const float4*)(xx + (size_t)edA.x * 4);
  float4 xB = *(const float4*)(xx + (size_t)edB.x * 4);
  for (int k = kb; k < ke; k += 2) {
    const int i2 = k + 2 < ke ? k + 2 : ke - 1;
    const int i3 = k + 3 < ke ? k + 3 : ke - 1;
    const int2 edC = cedge[i2], edD = cedge[i3];
    const float4 xC = *(const float4*)(xx + (size_t)edC.x * 4);
    const float4 xD = *(const float4*)(xx + (size_t)edD.x * 4);
    G1_EDGE(xA, __int_as_float(edA.y));
    if (k + 1 < ke) {          // wave-uniform guard
      G1_EDGE(xB, __int_as_float(edB.y));
    }
    xA = xC; edA = edC; xB = xD; edB = edD;
  }
#undef G1_EDGE

  float rd = 1.f / den;
  float4 bv = *(const float4*)(bias + j0);
  float bb[4] = {bv.x, bv.y, bv.z, bv.w};
  short hi[4], lo[4];
#pragma unroll
  for (int c = 0; c < 4; c++) {
    float hv = tanhf(fmaf(acc[c], rd, bb[c]));
    unsigned short hb = f2bf(hv);
    hi[c] = (short)hb;
    lo[c] = (short)f2bf(hv - bf2f(hb));
  }
  *(short4v*)(ah + (size_t)node * 256 + j0) = *(short4v*)hi;
  *(short4v*)(al + (size_t)node * 256 + j0) = *(short4v*)lo;
}

// ---------- W2 = [wl2 | wr2] transposed to [n][k], split hi/lo ----------
__global__ void k_wsplit(const float* __restrict__ wl, const float* __restrict__ wr,
                         short* __restrict__ bh, short* __restrict__ bl) {
  int id = blockIdx.x * 256 + threadIdx.x;  // 65536
  int n = id >> 8, k = id & 255;
  float w = n < 128 ? wl[k * 128 + n] : wr[k * 128 + n - 128];
  unsigned short hb = f2bf(w);
  bh[n * 256 + k] = (short)hb;
  bl[n * 256 + k] = (short)f2bf(w - bf2f(hb));
}

// layer-2 GEMM (known-good): BM=128 x BN=64, BK=32; single K-sweep,
// acc += Ah·Bh + Ah·Bl + Al·Bh per tile. xl output fp16, xr f32.
__global__ __launch_bounds__(256) void k_gemm2(const short* __restrict__ ah,
                                               const short* __restrict__ al,
                                               const short* __restrict__ bh,
                                               const short* __restrict__ bl,
                                               _Float16* __restrict__ xlh,
                                               float* __restrict__ xr) {
  __shared__ short sAh[128 * 40];
  __shared__ short sAl[128 * 40];
  __shared__ short sBh[64 * 40];
  __shared__ short sBl[64 * 40];
  const int tid = threadIdx.x;
  const int bm = blockIdx.x >> 2, bn = blockIdx.x & 3;
  const int wid = tid >> 6, lane = tid & 63;
  const int wr = wid >> 1, wc = wid & 1;
  const int l15 = lane & 15, lhi = lane >> 4;
  const int srow = tid >> 2;
  const int kq = (tid & 3) * 8;
  f32x4 acc[4][2];
#pragma unroll
  for (int a = 0; a < 4; a++)
#pragma unroll
    for (int b = 0; b < 2; b++) acc[a][b] = (f32x4)(0.f);

#pragma unroll 1
  for (int st = 0; st < 8; st++) {
    const int k0 = st * 32;
    const long aoff0 = (long)(bm * 128 + srow) * 256 + k0 + kq;
    const long aoff1 = aoff0 + 64 * 256;
    const long boff = (long)(bn * 64 + srow) * 256 + k0 + kq;
    short8 vah0 = *(const short8*)(ah + aoff0);
    short8 vah1 = *(const short8*)(ah + aoff1);
    short8 val0 = *(const short8*)(al + aoff0);
    short8 val1 = *(const short8*)(al + aoff1);
    short8 vbh  = *(const short8*)(bh + boff);
    short8 vbl  = *(const short8*)(bl + boff);
    __syncthreads();
    *(short8*)&sAh[srow * 40 + kq] = vah0;
    *(short8*)&sAh[(64 + srow) * 40 + kq] = vah1;
    *(short8*)&sAl[srow * 40 + kq] = val0;
    *(short8*)&sAl[(64 + srow) * 40 + kq] = val1;
    *(short8*)&sBh[srow * 40 + kq] = vbh;
    *(short8*)&sBl[srow * 40 + kq] = vbl;
    __syncthreads();
    short8 bfh[2], bfl[2];
#pragma unroll
    for (int fn = 0; fn < 2; fn++) {
      bfh[fn] = *(const short8*)&sBh[(wc * 32 + fn * 16 + l15) * 40 + lhi * 8];
      bfl[fn] = *(const short8*)&sBl[(wc * 32 + fn * 16 + l15) * 40 + lhi * 8];
    }
#pragma unroll
    for (int fm = 0; fm < 4; fm++) {
      short8 afh = *(const short8*)&sAh[(wr * 64 + fm * 16 + l15) * 40 + lhi * 8];
      short8 afl = *(const short8*)&sAl[(wr * 64 + fm * 16 + l15) * 40 + lhi * 8];
      acc[fm][0] = __builtin_amdgcn_mfma_f32_16x16x32_bf16(afh, bfh[0], acc[fm][0], 0, 0, 0);
      acc[fm][1] = __builtin_amdgcn_mfma_f32_16x16x32_bf16(afh, bfh[1], acc[fm][1], 0, 0, 0);
      acc[fm][0] = __builtin_amdgcn_mfma_f32_16x16x32_bf16(afh, bfl[0], acc[fm][0], 0, 0, 0);
      acc[fm][1] = __builtin_amdgcn_mfma_f32_16x16x32_bf16(afh, bfl[1], acc[fm][1], 0, 0, 0);
      acc[fm][0] = __builtin_amdgcn_mfma_f32_16x16x32_bf16(afl, bfh[0], acc[fm][0], 0, 0, 0);
      acc[fm][1] = __builtin_amdgcn_mfma_f32_16x16x32_bf16(afl, bfh[1], acc[fm][1], 0, 0, 0);
    }
  }
#pragma unroll
  for (int fm = 0; fm < 4; fm++)
#pragma unroll
    for (int fn = 0; fn < 2; fn++) {
      int col = bn * 64 + wc * 32 + fn * 16 + l15;
#pragma unroll
      for (int j = 0; j < 4; j++) {
        int row = bm * 128 + wr * 64 + fm * 16 + lhi * 4 + j;
        if (col < 128) xlh[(long)row * 128 + col] = (_Float16)acc[fm][fn][j];
        else           xr[(long)row * 128 + col - 128] = acc[fm][fn][j];
      }
    }
}

// ---------- layer 2 gather: fp16 xl, O=128; 4-edge-deep prefetch ----------
__global__ __launch_bounds__(256) void k_gat2(const int* __restrict__ rowptr,
                                              const int2* __restrict__ cedge,
                                              const _Float16* __restrict__ xlh,
                                              const float* __restrict__ xr,
                                              const float* __restrict__ we,
                                              const float* __restrict__ att,
                                              const float* __restrict__ bias,
                                              float* __restrict__ hout) {
  const int lane = threadIdx.x & 63;
  const int node = __builtin_amdgcn_readfirstlane(blockIdx.x * 4 + (threadIdx.x >> 6));
  if (node >= NN) return;
  const int j0 = lane * 2;
  float2 xrr = *(const float2*)(xr + (long)node * 128 + j0);
  float2 wev = *(const float2*)(we + j0);
  float2 attv = *(const float2*)(att + j0);
  float m = -INFINITY, den = 0.f, acc0 = 0.f, acc1 = 0.f;
  const int kb = rowptr[node], ke = rowptr[node + 1];

#define G2_EDGE(AV, EAV)                                                  \
  {                                                                       \
    float av0 = (float)(AV).x, av1 = (float)(AV).y;                       \
    float v0 = lrelu(av0 + fmaf((EAV), wev.x, xrr.x));                    \
    float v1 = lrelu(av1 + fmaf((EAV), wev.y, xrr.y));                    \
    float p = red8(fmaf(v0, attv.x, v1 * attv.y));                        \
    if (!__all(p <= m + 8.f)) {                                           \
      float mn = fmaxf(m, p);                                             \
      float sc = __expf(m - mn);                                          \
      den *= sc;                                                          \
      acc0 *= sc;                                                         \
      acc1 *= sc;                                                         \
      m = mn;                                                             \
    }                                                                     \
    float ex = __expf(p - m);                                             \
    den += ex;                                                            \
    acc0 = fmaf(ex, av0, acc0);                                           \
    acc1 = fmaf(ex, av1, acc1);                                           \
  }

  // 4-deep prologue
  int p1 = kb + 1 < ke ? kb + 1 : ke - 1;
  int p2 = kb + 2 < ke ? kb + 2 : ke - 1;
  int p3 = kb + 3 < ke ? kb + 3 : ke - 1;
  int2 ed0 = cedge[kb], ed1 = cedge[p1], ed2 = cedge[p2], ed3 = cedge[p3];
  half2v a0 = *(const half2v*)(xlh + (long)ed0.x * 128 + j0);
  half2v a1 = *(const half2v*)(xlh + (long)ed1.x * 128 + j0);
  half2v a2 = *(const half2v*)(xlh + (long)ed2.x * 128 + j0);
  half2v a3 = *(const half2v*)(xlh + (long)ed3.x * 128 + j0);
  for (int k = kb; k < ke; k += 4) {
    const int q0 = k + 4 < ke ? k + 4 : ke - 1;
    const int q1 = k + 5 < ke ? k + 5 : ke - 1;
    const int q2 = k + 6 < ke ? k + 6 : ke - 1;
    const int q3 = k + 7 < ke ? k + 7 : ke - 1;
    const int2 nd0 = cedge[q0], nd1 = cedge[q1], nd2 = cedge[q2], nd3 = cedge[q3];
    const half2v b0 = *(const half2v*)(xlh + (long)nd0.x * 128 + j0);
    const half2v b1 = *(const half2v*)(xlh + (long)nd1.x * 128 + j0);
    const half2v b2 = *(const half2v*)(xlh + (long)nd2.x * 128 + j0);
    const half2v b3 = *(const half2v*)(xlh + (long)nd3.x * 128 + j0);
    G2_EDGE(a0, __int_as_float(ed0.y));
    if (k + 1 < ke) G2_EDGE(a1, __int_as_float(ed1.y));
    if (k + 2 < ke) G2_EDGE(a2, __int_as_float(ed2.y));
    if (k + 3 < ke) G2_EDGE(a3, __int_as_float(ed3.y));
    a0 = b0; ed0 = nd0; a1 = b1; ed1 = nd1;
    a2 = b2; ed2 = nd2; a3 = b3; ed3 = nd3;
  }
#undef G2_EDGE

  float rd = 1.f / den;
  hout[(long)node * 128 + j0]     = tanhf(fmaf(acc0, rd, bias[j0]));
  hout[(long)node * 128 + j0 + 1] = tanhf(fmaf(acc1, rd, bias[j0 + 1]));
}

// ---------- layer 3 transform: 64 nodes/block, LDS-staged ----------
__global__ __launch_bounds__(256) void k_mm3(const float* __restrict__ h,
                                             const float* __restrict__ wl,
                                             const float* __restrict__ wr,
                                             float* __restrict__ xl,
                                             float* __restrict__ xr) {
  __shared__ float srow[64 * 132];
  __shared__ float lw[128 * 16];
  const int t = threadIdx.x;
  const int n0 = blockIdx.x * 64;
#pragma unroll
  for (int q = 0; q < 8; q++) {
    int gi = (t + q * 256) * 4;
    int row = gi >> 7, col = gi & 127;
    float4 v = *(const float4*)(h + (size_t)(n0 + row) * 128 + col);
    *(float4*)&srow[row * 132 + col] = v;
  }
#pragma unroll
  for (int q = 0; q < 8; q++) {
    int idx = t + q * 256;
    int k = idx >> 4, j = idx & 15;
    lw[idx] = j < 8 ? wl[k * 8 + j] : wr[k * 8 + (j - 8)];
  }
  __syncthreads();
  const int nid = t >> 2, g = t & 3;
  float a0 = 0.f, a1 = 0.f, a2 = 0.f, a3 = 0.f;
  const float* rp = &srow[nid * 132];
  for (int k = 0; k < 128; k++) {
    float hv = rp[k];
    float4 w = *(const float4*)&lw[k * 16 + g * 4];
    a0 = fmaf(hv, w.x, a0);
    a1 = fmaf(hv, w.y, a1);
    a2 = fmaf(hv, w.z, a2);
    a3 = fmaf(hv, w.w, a3);
  }
  float4 r = {a0, a1, a2, a3};
  int node = n0 + nid;
  float* dst = (g & 2) ? xr : xl;
  *(float4*)(dst + node * 8 + (g & 1) * 4) = r;
}

// ---------- layer 3 gather: O=8, H=1, 8-lane group per node; 2-deep prefetch ----------
__global__ __launch_bounds__(256) void k_gat3(const int* __restrict__ rowptr,
                                              const int2* __restrict__ cedge,
                                              const float* __restrict__ xl,
                                              const float* __restrict__ xr,
                                              const float* __restrict__ we,
                                              const float* __restrict__ att,
                                              const float* __restrict__ bias,
                                              float* __restrict__ hout) {
  const int lane = threadIdx.x & 7;
  const int node = blockIdx.x * 32 + (threadIdx.x >> 3);
  if (node >= NN) return;
  const float xrr = xr[node * 8 + lane];
  const float wev = we[lane];
  const float attv = att[lane];
  float m = -INFINITY, den = 0.f, acc = 0.f;
  const int kb = rowptr[node], ke = rowptr[node + 1];

#define G3_EDGE(AV, EAV)                                      \
  {                                                           \
    float v = lrelu((AV) + fmaf((EAV), wev, xrr));            \
    float p = red8(v * attv);                                 \
    if (p > m + 8.f) {                                        \
      float mn = fmaxf(m, p);                                 \
      float sc = __expf(m - mn);                              \
      den *= sc;                                              \
      acc *= sc;                                              \
      m = mn;                                                 \
    }                                                         \
    float ex = __expf(p - m);                                 \
    den += ex;                                                \
    acc = fmaf(ex, (AV), acc);                                \
  }

  int i1 = kb + 1 < ke ? kb + 1 : ke - 1;
  int2 edA = cedge[kb], edB = cedge[i1];
  float aA = xl[edA.x * 8 + lane];
  float aB = xl[edB.x * 8 + lane];
  for (int k = kb; k < ke; k += 2) {
    const int i2 = k + 2 < ke ? k + 2 : ke - 1;
    const int i3 = k + 3 < ke ? k + 3 : ke - 1;
    const int2 edC = cedge[i2], edD = cedge[i3];
    const float aC = xl[edC.x * 8 + lane];
    const float aD = xl[edD.x * 8 + lane];
    G3_EDGE(aA, __int_as_float(edA.y));
    if (k + 1 < ke) {
      G3_EDGE(aB, __int_as_float(edB.y));
    }
    aA = aC; edA = edC; aB = aD; edB = edD;
  }
#undef G3_EDGE

  hout[node * 8 + lane] = tanhf(acc / den + bias[lane]);
}

// one wave per graph: segmented mean-pool + head, no atomics.
__global__ __launch_bounds__(256) void k_poolG(const int* __restrict__ gstart,
                                               const float* __restrict__ h3,
                                               const float* __restrict__ w4,
                                               const float* __restrict__ b4,
                                               float* __restrict__ out) {
  const int lane = threadIdx.x & 63;
  const int g = blockIdx.x * 4 + (threadIdx.x >> 6);
  if (g >= NB) return;
  const int kb = gstart[g], ke = gstart[g + 1];
  const int ch = lane & 7, no = lane >> 3;
  float acc = 0.f;
  for (int n = kb + no; n < ke; n += 8)
    acc += h3[(size_t)n * 8 + ch];
  acc += __shfl_xor(acc, 8);
  acc += __shfl_xor(acc, 16);
  acc += __shfl_xor(acc, 32);
  float cnt = fmaxf((float)(ke - kb), 1.f);
  float yv = (acc / cnt) * w4[ch];
  yv = red8(yv);
  if (lane == 0) out[g] = yv + b4[0];
}

extern "C" void kernel_launch(void* const* d_in, const int* in_sizes, int n_in,
                              void* d_out, int out_size, void* d_ws, size_t ws_size,
                              hipStream_t stream) {
  const float* x   = (const float*)d_in[0];
  const int*   ei  = (const int*)d_in[1];
  const float* ea  = (const float*)d_in[2];
  const int*   bat = (const int*)d_in[3];
  const float* w0  = (const float*)d_in[4];
  const float* b0  = (const float*)d_in[5];
  const float* wl1 = (const float*)d_in[6];
  const float* wr1 = (const float*)d_in[7];
  const float* we1 = (const float*)d_in[8];
  const float* at1 = (const float*)d_in[9];
  const float* b1  = (const float*)d_in[10];
  const float* wl2 = (const float*)d_in[11];
  const float* wr2 = (const float*)d_in[12];
  const float* we2 = (const float*)d_in[13];
  const float* at2 = (const float*)d_in[14];
  const float* b2  = (const float*)d_in[15];
  const float* wl3 = (const float*)d_in[16];
  const float* wr3 = (const float*)d_in[17];
  const float* we3 = (const float*)d_in[18];
  const float* at3 = (const float*)d_in[19];
  const float* b3  = (const float*)d_in[20];
  const float* w4  = (const float*)d_in[21];
  const float* b4  = (const float*)d_in[22];
  float* out = (float*)d_out;

  char* W = (char*)d_ws;
  size_t o = 0;
  auto alloc = [&](size_t bytes) { void* p = W + o; o += (bytes + 255) & ~(size_t)255; return p; };
  int*      degi   = (int*)alloc(NN * 4);   // degi/fillc/lpa contiguous (one memset)
  int*      fillc  = (int*)alloc(NN * 4);
  float*    lpa    = (float*)alloc(NN * 4);
  int*      rowptr = (int*)alloc((NN + 1) * 4);
  int*      pre    = (int*)alloc(NN * 4);
  int*      bsum   = (int*)alloc(256 * 4);
  int*      gstart = (int*)alloc((NB + 1) * 4);
  int2*     cedge  = (int2*)alloc((size_t)NEF * 8);
  short*    Ah     = (short*)alloc((size_t)NNP * 256 * 2);
  short*    Al     = (short*)alloc((size_t)NNP * 256 * 2);
  short*    Bh     = (short*)alloc((size_t)256 * 256 * 2);
  short*    Bl     = (short*)alloc((size_t)256 * 256 * 2);
  _Float16* Xlh2   = (_Float16*)alloc((size_t)NNP * 128 * 2);
  float*    Xr2    = (float*)alloc((size_t)NNP * 128 * 4);
  float*    H2     = (float*)alloc((size_t)NN * 128 * 4);
  float*    Xl3    = (float*)alloc((size_t)NN * 8 * 4);
  float*    Xr3    = (float*)alloc((size_t)NN * 8 * 4);
  float*    H3     = (float*)alloc((size_t)NN * 8 * 4);
  (void)ws_size; (void)in_sizes; (void)n_in; (void)out_size;

  const int NBLK = cdiv(NN, 256);  // == NBLK_C

  // ---- CSR build (+ graph bounds merged into scanA) ----
  hipMemsetAsync(degi, 0, 3 * NN * 4, stream);  // degi + fillc + lpa
  k_deg<<<cdiv(NE, 256), 256, 0, stream>>>(ei, ea, degi, lpa);
  k_scanA<<<NBLK, 256, 0, stream>>>(degi, pre, bsum, lpa, bat, gstart);
  k_scan3<<<NBLK, 256, 0, stream>>>(pre, bsum, rowptr);
  k_fill<<<cdiv(NEF, 256), 256, 0, stream>>>(ei, ea, lpa, rowptr, fillc, cedge);

  // ---- layer 1 (fused transform+gather from raw x; emits bf16 hi/lo h1) ----
  k_gat1<<<NNP / 4, 256, 0, stream>>>(rowptr, cedge, x, w0, b0, wl1, wr1, we1, at1, b1, Ah, Al);

  // ---- layer 2: MFMA GEMM (BM=128) + fp16 gather ----
  k_wsplit<<<256, 256, 0, stream>>>(wl2, wr2, Bh, Bl);
  k_gemm2<<<(NNP / 128) * 4, 256, 0, stream>>>(Ah, Al, Bh, Bl, Xlh2, Xr2);
  k_gat2<<<cdiv(NN, 4), 256, 0, stream>>>(rowptr, cedge, Xlh2, Xr2, we2, at2, b2, H2);

  // ---- layer 3 ----
  k_mm3<<<NN / 64, 256, 0, stream>>>(H2, wl3, wr3, Xl3, Xr3);
  k_gat3<<<cdiv(NN, 32), 256, 0, stream>>>(rowptr, cedge, Xl3, Xr3, we3, at3, b3, H3);

  // ---- pooling + head (segmented, no atomics) ----
  k_poolG<<<cdiv(NB, 4), 256, 0, stream>>>(gstart, H3, w4, b4, out);
}

// Round 14
// 223.660 us; speedup vs baseline: 1.0614x; 1.0446x over previous
//
#include <hip/hip_runtime.h>
#include <math.h>

#define NN 40000
#define NNP 40192              // NN padded (multiple of 128) for MFMA GEMM
#define NE 500000
#define NEF (NN + NE)
#define NB 512
#define NEG 0.2f
#define NBLK_C 157             // cdiv(NN,256)

static inline int cdiv(int a, int b) { return (a + b - 1) / b; }

typedef __attribute__((ext_vector_type(8))) short short8;
typedef __attribute__((ext_vector_type(4))) short short4v;
typedef __attribute__((ext_vector_type(4))) float f32x4;
typedef __attribute__((ext_vector_type(2))) _Float16 half2v;

__device__ __forceinline__ unsigned short f2bf(float f) {
  unsigned u = __float_as_uint(f);
  unsigned r = (u + 0x7fffu + ((u >> 16) & 1u)) >> 16;
  return (unsigned short)r;
}
__device__ __forceinline__ float bf2f(unsigned short h) {
  return __uint_as_float((unsigned)h << 16);
}
__device__ __forceinline__ float lrelu(float v) {
  return fmaxf(v, NEG * v);   // NEG in (0,1): max(v, 0.2v) == leaky_relu(v)
}
// sum over each aligned 8-lane group, DPP only:
__device__ __forceinline__ float red8(float p) {
  p += __uint_as_float((unsigned)__builtin_amdgcn_mov_dpp((int)__float_as_uint(p), 0xB1, 0xF, 0xF, true));
  p += __uint_as_float((unsigned)__builtin_amdgcn_mov_dpp((int)__float_as_uint(p), 0x4E, 0xF, 0xF, true));
  p += __uint_as_float((unsigned)__builtin_amdgcn_mov_dpp((int)__float_as_uint(p), 0x141, 0xF, 0xF, true));
  return p;
}

// ---------- self-loop attr prep ----------
__global__ void k_deg(const int* __restrict__ ei, const float* __restrict__ ea,
                      int* __restrict__ degi, float* __restrict__ esum) {
  int e = blockIdx.x * 256 + threadIdx.x;
  if (e < NE) {
    int d = ei[NE + e];
    atomicAdd(degi + d, 1);
    atomicAdd(esum + d, ea[e]);
  }
}

// scan1 + lpa finalize + graph-boundary detection (merged; same i<NN grid)
__global__ void k_scanA(const int* __restrict__ degi, int* __restrict__ pre,
                        int* __restrict__ bsum, float* __restrict__ lpa,
                        const int* __restrict__ bat, int* __restrict__ gstart) {
  __shared__ int sh[256];
  int t = threadIdx.x, i = blockIdx.x * 256 + t;
  int dg = i < NN ? degi[i] : -1;
  sh[t] = i < NN ? dg + 1 : 0;   // +1 self loop
  if (i < NN) {
    lpa[i] = dg > 0 ? lpa[i] / (float)dg : 0.f;
    int b = bat[i];
    int bp = i > 0 ? bat[i - 1] : -1;
    for (int g = bp + 1; g <= b; g++) gstart[g] = i;
    if (i == NN - 1)
      for (int g = b + 1; g <= NB; g++) gstart[g] = NN;
  }
  __syncthreads();
  for (int st = 1; st < 256; st <<= 1) {
    int a = t >= st ? sh[t - st] : 0;
    __syncthreads();
    sh[t] += a;
    __syncthreads();
  }
  if (i < NN) pre[i] = sh[t];
  if (t == 255) bsum[blockIdx.x] = sh[255];
}

// scan3 with block-sum prefix computed locally (NBLK_C <= 256)
__global__ void k_scan3(const int* __restrict__ pre, const int* __restrict__ bsum,
                        int* __restrict__ rowptr) {
  __shared__ int sh[256];
  int t = threadIdx.x;
  sh[t] = t < NBLK_C ? bsum[t] : 0;
  __syncthreads();
  for (int st = 1; st < 256; st <<= 1) {
    int a = t >= st ? sh[t - st] : 0;
    __syncthreads();
    sh[t] += a;
    __syncthreads();
  }
  int i = blockIdx.x * 256 + t;
  if (i < NN) {
    int off = blockIdx.x > 0 ? sh[blockIdx.x - 1] : 0;
    rowptr[i + 1] = pre[i] + off;
    if (i == 0) rowptr[0] = 0;
  }
}

// fill CSR with packed {src, eav} records (one 8B store per edge)
__global__ void k_fill(const int* __restrict__ ei, const float* __restrict__ ea,
                       const float* __restrict__ lpa, const int* __restrict__ rowptr,
                       int* __restrict__ fillc, int2* __restrict__ cedge) {
  int e = blockIdx.x * 256 + threadIdx.x;
  if (e >= NEF) return;
  int s, d;
  float v;
  if (e < NE) { s = ei[e]; d = ei[NE + e]; v = ea[e]; }
  else        { s = e - NE; d = s; v = lpa[s]; }
  int pos = atomicAdd(fillc + d, 1);
  int idx = rowptr[d] + pos;
  cedge[idx] = make_int2(s, __float_as_int(v));
}

// ---------- layer 1 fully fused, strength-reduced; 2-edge-deep prefetch ----------
__global__ __launch_bounds__(256) void k_gat1(const int* __restrict__ rowptr,
                                              const int2* __restrict__ cedge,
                                              const float* __restrict__ xx,
                                              const float* __restrict__ w0,
                                              const float* __restrict__ b0,
                                              const float* __restrict__ wl,
                                              const float* __restrict__ wr,
                                              const float* __restrict__ we,
                                              const float* __restrict__ att,
                                              const float* __restrict__ bias,
                                              short* __restrict__ ah,
                                              short* __restrict__ al) {
  const int lane = threadIdx.x & 63;
  const int node = __builtin_amdgcn_readfirstlane(blockIdx.x * 4 + (threadIdx.x >> 6));
  const int j0 = lane * 4;
  if (node >= NN) {  // zero GEMM pad rows (node < NNP by grid construction)
    short4v z = {0, 0, 0, 0};
    *(short4v*)(ah + (size_t)node * 256 + j0) = z;
    *(short4v*)(al + (size_t)node * 256 + j0) = z;
    return;
  }

  float4 wev = *(const float4*)(we + j0);
  float4 attv = *(const float4*)(att + j0);
  float w0s[4] = {w0[0], w0[1], w0[2], w0[3]};
  float b0s[4] = {b0[0], b0[1], b0[2], b0[3]};
  float u[4] = {0.f, 0.f, 0.f, 0.f}, v[4] = {0.f, 0.f, 0.f, 0.f};
#pragma unroll
  for (int j = 0; j < 4; j++) {
    float4 t = *(const float4*)(wl + j * 256 + j0);
    float tt[4] = {t.x, t.y, t.z, t.w};
#pragma unroll
    for (int c = 0; c < 4; c++) {
      u[c] = fmaf(w0s[j], tt[c], u[c]);
      v[c] = fmaf(b0s[j], tt[c], v[c]);
    }
  }
  float4 wl4 = *(const float4*)(wl + 4 * 256 + j0);
  float4 wl5 = *(const float4*)(wl + 5 * 256 + j0);
  float4 wl6 = *(const float4*)(wl + 6 * 256 + j0);

  float xrr[4] = {0.f, 0.f, 0.f, 0.f};
  {
    float4 xv = *(const float4*)(xx + (size_t)node * 4);
    float hn[7] = {fmaf(xv.x, w0s[0], b0s[0]), fmaf(xv.x, w0s[1], b0s[1]),
                   fmaf(xv.x, w0s[2], b0s[2]), fmaf(xv.x, w0s[3], b0s[3]),
                   xv.y, xv.z, xv.w};
#pragma unroll
    for (int k = 0; k < 7; k++) {
      float4 t = *(const float4*)(wr + k * 256 + j0);
      xrr[0] = fmaf(hn[k], t.x, xrr[0]);
      xrr[1] = fmaf(hn[k], t.y, xrr[1]);
      xrr[2] = fmaf(hn[k], t.z, xrr[2]);
      xrr[3] = fmaf(hn[k], t.w, xrr[3]);
    }
  }

  float m = -INFINITY, den = 0.f;
  float acc[4] = {0.f, 0.f, 0.f, 0.f};
  const int kb = rowptr[node], ke = rowptr[node + 1];

#define G1_EDGE(XS, EAV)                                                        \
  {                                                                             \
    float xls[4];                                                               \
    _Pragma("unroll")                                                           \
    for (int c = 0; c < 4; c++) xls[c] = fmaf((XS).x, u[c], v[c]);              \
    xls[0] = fmaf((XS).y, wl4.x, xls[0]); xls[1] = fmaf((XS).y, wl4.y, xls[1]); \
    xls[2] = fmaf((XS).y, wl4.z, xls[2]); xls[3] = fmaf((XS).y, wl4.w, xls[3]); \
    xls[0] = fmaf((XS).z, wl5.x, xls[0]); xls[1] = fmaf((XS).z, wl5.y, xls[1]); \
    xls[2] = fmaf((XS).z, wl5.z, xls[2]); xls[3] = fmaf((XS).z, wl5.w, xls[3]); \
    xls[0] = fmaf((XS).w, wl6.x, xls[0]); xls[1] = fmaf((XS).w, wl6.y, xls[1]); \
    xls[2] = fmaf((XS).w, wl6.z, xls[2]); xls[3] = fmaf((XS).w, wl6.w, xls[3]); \
    float p = 0.f;                                                              \
    p = fmaf(lrelu(xls[0] + fmaf((EAV), wev.x, xrr[0])), attv.x, p);            \
    p = fmaf(lrelu(xls[1] + fmaf((EAV), wev.y, xrr[1])), attv.y, p);            \
    p = fmaf(lrelu(xls[2] + fmaf((EAV), wev.z, xrr[2])), attv.z, p);            \
    p = fmaf(lrelu(xls[3] + fmaf((EAV), wev.w, xrr[3])), attv.w, p);            \
    p = red8(p);                                                                \
    if (!__all(p <= m + 8.f)) {                                                 \
      float mn = fmaxf(m, p);                                                   \
      float sc = __expf(m - mn);                                                \
      den *= sc;                                                                \
      _Pragma("unroll")                                                         \
      for (int c = 0; c < 4; c++) acc[c] *= sc;                                 \
      m = mn;                                                                   \
    }                                                                           \
    float ex = __expf(p - m);                                                   \
    den += ex;                                                                  \
    _Pragma("unroll")                                                           \
    for (int c = 0; c < 4; c++) acc[c] = fmaf(ex, xls[c], acc[c]);              \
  }

  int i1 = kb + 1 < ke ? kb + 1 : ke - 1;
  int2 edA = cedge[kb], edB = cedge[i1];
  float4 xA = *(const float4*)(xx + (size_t)edA.x * 4);
  float4 xB = *(const float4*)(xx + (size_t)edB.x * 4);
  for (int k = kb; k < ke; k += 2) {
    const int i2 = k + 2 < ke ? k + 2 : ke - 1;
    const int i3 = k + 3 < ke ? k + 3 : ke - 1;
    const int2 edC = cedge[i2], edD = cedge[i3];
    const float4 xC = *(const float4*)(xx + (size_t)edC.x * 4);
    const float4 xD = *(const float4*)(xx + (size_t)edD.x * 4);
    G1_EDGE(xA, __int_as_float(edA.y));
    if (k + 1 < ke) {          // wave-uniform guard
      G1_EDGE(xB, __int_as_float(edB.y));
    }
    xA = xC; edA = edC; xB = xD; edB = edD;
  }
#undef G1_EDGE

  float rd = 1.f / den;
  float4 bv = *(const float4*)(bias + j0);
  float bb[4] = {bv.x, bv.y, bv.z, bv.w};
  short hi[4], lo[4];
#pragma unroll
  for (int c = 0; c < 4; c++) {
    float hv = tanhf(fmaf(acc[c], rd, bb[c]));
    unsigned short hb = f2bf(hv);
    hi[c] = (short)hb;
    lo[c] = (short)f2bf(hv - bf2f(hb));
  }
  *(short4v*)(ah + (size_t)node * 256 + j0) = *(short4v*)hi;
  *(short4v*)(al + (size_t)node * 256 + j0) = *(short4v*)lo;
}

// ---------- W2 = [wl2 | wr2] transposed to [n][k], split hi/lo ----------
__global__ void k_wsplit(const float* __restrict__ wl, const float* __restrict__ wr,
                         short* __restrict__ bh, short* __restrict__ bl) {
  int id = blockIdx.x * 256 + threadIdx.x;  // 65536
  int n = id >> 8, k = id & 255;
  float w = n < 128 ? wl[k * 128 + n] : wr[k * 128 + n - 128];
  unsigned short hb = f2bf(w);
  bh[n * 256 + k] = (short)hb;
  bl[n * 256 + k] = (short)f2bf(w - bf2f(hb));
}

// layer-2 GEMM: BM=128 x BN=64, BK=32; single K-sweep,
// acc += Ah·Bh + Ah·Bl + Al·Bh per tile. xl output fp16, xr f32.
// XCD-chunked swizzle (isolated this round): nwg = 1256 = 8*157, bijective;
// the 4 bn-blocks of one bm-tile land on one XCD -> A-tile read from HBM once.
__global__ __launch_bounds__(256) void k_gemm2(const short* __restrict__ ah,
                                               const short* __restrict__ al,
                                               const short* __restrict__ bh,
                                               const short* __restrict__ bl,
                                               _Float16* __restrict__ xlh,
                                               float* __restrict__ xr) {
  __shared__ short sAh[128 * 40];
  __shared__ short sAl[128 * 40];
  __shared__ short sBh[64 * 40];
  __shared__ short sBl[64 * 40];
  const int tid = threadIdx.x;
  const int wgid = (blockIdx.x & 7) * ((NNP / 128) * 4 / 8) + (blockIdx.x >> 3);
  const int bm = wgid >> 2, bn = wgid & 3;
  const int wid = tid >> 6, lane = tid & 63;
  const int wr = wid >> 1, wc = wid & 1;
  const int l15 = lane & 15, lhi = lane >> 4;
  const int srow = tid >> 2;
  const int kq = (tid & 3) * 8;
  f32x4 acc[4][2];
#pragma unroll
  for (int a = 0; a < 4; a++)
#pragma unroll
    for (int b = 0; b < 2; b++) acc[a][b] = (f32x4)(0.f);

#pragma unroll 1
  for (int st = 0; st < 8; st++) {
    const int k0 = st * 32;
    const long aoff0 = (long)(bm * 128 + srow) * 256 + k0 + kq;
    const long aoff1 = aoff0 + 64 * 256;
    const long boff = (long)(bn * 64 + srow) * 256 + k0 + kq;
    short8 vah0 = *(const short8*)(ah + aoff0);
    short8 vah1 = *(const short8*)(ah + aoff1);
    short8 val0 = *(const short8*)(al + aoff0);
    short8 val1 = *(const short8*)(al + aoff1);
    short8 vbh  = *(const short8*)(bh + boff);
    short8 vbl  = *(const short8*)(bl + boff);
    __syncthreads();
    *(short8*)&sAh[srow * 40 + kq] = vah0;
    *(short8*)&sAh[(64 + srow) * 40 + kq] = vah1;
    *(short8*)&sAl[srow * 40 + kq] = val0;
    *(short8*)&sAl[(64 + srow) * 40 + kq] = val1;
    *(short8*)&sBh[srow * 40 + kq] = vbh;
    *(short8*)&sBl[srow * 40 + kq] = vbl;
    __syncthreads();
    short8 bfh[2], bfl[2];
#pragma unroll
    for (int fn = 0; fn < 2; fn++) {
      bfh[fn] = *(const short8*)&sBh[(wc * 32 + fn * 16 + l15) * 40 + lhi * 8];
      bfl[fn] = *(const short8*)&sBl[(wc * 32 + fn * 16 + l15) * 40 + lhi * 8];
    }
#pragma unroll
    for (int fm = 0; fm < 4; fm++) {
      short8 afh = *(const short8*)&sAh[(wr * 64 + fm * 16 + l15) * 40 + lhi * 8];
      short8 afl = *(const short8*)&sAl[(wr * 64 + fm * 16 + l15) * 40 + lhi * 8];
      acc[fm][0] = __builtin_amdgcn_mfma_f32_16x16x32_bf16(afh, bfh[0], acc[fm][0], 0, 0, 0);
      acc[fm][1] = __builtin_amdgcn_mfma_f32_16x16x32_bf16(afh, bfh[1], acc[fm][1], 0, 0, 0);
      acc[fm][0] = __builtin_amdgcn_mfma_f32_16x16x32_bf16(afh, bfl[0], acc[fm][0], 0, 0, 0);
      acc[fm][1] = __builtin_amdgcn_mfma_f32_16x16x32_bf16(afh, bfl[1], acc[fm][1], 0, 0, 0);
      acc[fm][0] = __builtin_amdgcn_mfma_f32_16x16x32_bf16(afl, bfh[0], acc[fm][0], 0, 0, 0);
      acc[fm][1] = __builtin_amdgcn_mfma_f32_16x16x32_bf16(afl, bfh[1], acc[fm][1], 0, 0, 0);
    }
  }
#pragma unroll
  for (int fm = 0; fm < 4; fm++)
#pragma unroll
    for (int fn = 0; fn < 2; fn++) {
      int col = bn * 64 + wc * 32 + fn * 16 + l15;
#pragma unroll
      for (int j = 0; j < 4; j++) {
        int row = bm * 128 + wr * 64 + fm * 16 + lhi * 4 + j;
        if (col < 128) xlh[(long)row * 128 + col] = (_Float16)acc[fm][fn][j];
        else           xr[(long)row * 128 + col - 128] = acc[fm][fn][j];
      }
    }
}

// ---------- layer 2 gather: fp16 xl, O=128; 4-edge-deep prefetch ----------
__global__ __launch_bounds__(256) void k_gat2(const int* __restrict__ rowptr,
                                              const int2* __restrict__ cedge,
                                              const _Float16* __restrict__ xlh,
                                              const float* __restrict__ xr,
                                              const float* __restrict__ we,
                                              const float* __restrict__ att,
                                              const float* __restrict__ bias,
                                              float* __restrict__ hout) {
  const int lane = threadIdx.x & 63;
  const int node = __builtin_amdgcn_readfirstlane(blockIdx.x * 4 + (threadIdx.x >> 6));
  if (node >= NN) return;
  const int j0 = lane * 2;
  float2 xrr = *(const float2*)(xr + (long)node * 128 + j0);
  float2 wev = *(const float2*)(we + j0);
  float2 attv = *(const float2*)(att + j0);
  float m = -INFINITY, den = 0.f, acc0 = 0.f, acc1 = 0.f;
  const int kb = rowptr[node], ke = rowptr[node + 1];

#define G2_EDGE(AV, EAV)                                                  \
  {                                                                       \
    float av0 = (float)(AV).x, av1 = (float)(AV).y;                       \
    float v0 = lrelu(av0 + fmaf((EAV), wev.x, xrr.x));                    \
    float v1 = lrelu(av1 + fmaf((EAV), wev.y, xrr.y));                    \
    float p = red8(fmaf(v0, attv.x, v1 * attv.y));                        \
    if (!__all(p <= m + 8.f)) {                                           \
      float mn = fmaxf(m, p);                                             \
      float sc = __expf(m - mn);                                          \
      den *= sc;                                                          \
      acc0 *= sc;                                                         \
      acc1 *= sc;                                                         \
      m = mn;                                                             \
    }                                                                     \
    float ex = __expf(p - m);                                             \
    den += ex;                                                            \
    acc0 = fmaf(ex, av0, acc0);                                           \
    acc1 = fmaf(ex, av1, acc1);                                           \
  }

  // 4-deep prologue
  int p1 = kb + 1 < ke ? kb + 1 : ke - 1;
  int p2 = kb + 2 < ke ? kb + 2 : ke - 1;
  int p3 = kb + 3 < ke ? kb + 3 : ke - 1;
  int2 ed0 = cedge[kb], ed1 = cedge[p1], ed2 = cedge[p2], ed3 = cedge[p3];
  half2v a0 = *(const half2v*)(xlh + (long)ed0.x * 128 + j0);
  half2v a1 = *(const half2v*)(xlh + (long)ed1.x * 128 + j0);
  half2v a2 = *(const half2v*)(xlh + (long)ed2.x * 128 + j0);
  half2v a3 = *(const half2v*)(xlh + (long)ed3.x * 128 + j0);
  for (int k = kb; k < ke; k += 4) {
    const int q0 = k + 4 < ke ? k + 4 : ke - 1;
    const int q1 = k + 5 < ke ? k + 5 : ke - 1;
    const int q2 = k + 6 < ke ? k + 6 : ke - 1;
    const int q3 = k + 7 < ke ? k + 7 : ke - 1;
    const int2 nd0 = cedge[q0], nd1 = cedge[q1], nd2 = cedge[q2], nd3 = cedge[q3];
    const half2v b0 = *(const half2v*)(xlh + (long)nd0.x * 128 + j0);
    const half2v b1 = *(const half2v*)(xlh + (long)nd1.x * 128 + j0);
    const half2v b2 = *(const half2v*)(xlh + (long)nd2.x * 128 + j0);
    const half2v b3 = *(const half2v*)(xlh + (long)nd3.x * 128 + j0);
    G2_EDGE(a0, __int_as_float(ed0.y));
    if (k + 1 < ke) G2_EDGE(a1, __int_as_float(ed1.y));
    if (k + 2 < ke) G2_EDGE(a2, __int_as_float(ed2.y));
    if (k + 3 < ke) G2_EDGE(a3, __int_as_float(ed3.y));
    a0 = b0; ed0 = nd0; a1 = b1; ed1 = nd1;
    a2 = b2; ed2 = nd2; a3 = b3; ed3 = nd3;
  }
#undef G2_EDGE

  float rd = 1.f / den;
  hout[(long)node * 128 + j0]     = tanhf(fmaf(acc0, rd, bias[j0]));
  hout[(long)node * 128 + j0 + 1] = tanhf(fmaf(acc1, rd, bias[j0 + 1]));
}

// ---------- layer 3 transform: 64 nodes/block, LDS-staged ----------
__global__ __launch_bounds__(256) void k_mm3(const float* __restrict__ h,
                                             const float* __restrict__ wl,
                                             const float* __restrict__ wr,
                                             float* __restrict__ xl,
                                             float* __restrict__ xr) {
  __shared__ float srow[64 * 132];
  __shared__ float lw[128 * 16];
  const int t = threadIdx.x;
  const int n0 = blockIdx.x * 64;
#pragma unroll
  for (int q = 0; q < 8; q++) {
    int gi = (t + q * 256) * 4;
    int row = gi >> 7, col = gi & 127;
    float4 v = *(const float4*)(h + (size_t)(n0 + row) * 128 + col);
    *(float4*)&srow[row * 132 + col] = v;
  }
#pragma unroll
  for (int q = 0; q < 8; q++) {
    int idx = t + q * 256;
    int k = idx >> 4, j = idx & 15;
    lw[idx] = j < 8 ? wl[k * 8 + j] : wr[k * 8 + (j - 8)];
  }
  __syncthreads();
  const int nid = t >> 2, g = t & 3;
  float a0 = 0.f, a1 = 0.f, a2 = 0.f, a3 = 0.f;
  const float* rp = &srow[nid * 132];
  for (int k = 0; k < 128; k++) {
    float hv = rp[k];
    float4 w = *(const float4*)&lw[k * 16 + g * 4];
    a0 = fmaf(hv, w.x, a0);
    a1 = fmaf(hv, w.y, a1);
    a2 = fmaf(hv, w.z, a2);
    a3 = fmaf(hv, w.w, a3);
  }
  float4 r = {a0, a1, a2, a3};
  int node = n0 + nid;
  float* dst = (g & 2) ? xr : xl;
  *(float4*)(dst + node * 8 + (g & 1) * 4) = r;
}

// ---------- layer 3 gather: O=8, H=1, 8-lane group per node; 2-deep prefetch ----------
__global__ __launch_bounds__(256) void k_gat3(const int* __restrict__ rowptr,
                                              const int2* __restrict__ cedge,
                                              const float* __restrict__ xl,
                                              const float* __restrict__ xr,
                                              const float* __restrict__ we,
                                              const float* __restrict__ att,
                                              const float* __restrict__ bias,
                                              float* __restrict__ hout) {
  const int lane = threadIdx.x & 7;
  const int node = blockIdx.x * 32 + (threadIdx.x >> 3);
  if (node >= NN) return;
  const float xrr = xr[node * 8 + lane];
  const float wev = we[lane];
  const float attv = att[lane];
  float m = -INFINITY, den = 0.f, acc = 0.f;
  const int kb = rowptr[node], ke = rowptr[node + 1];

#define G3_EDGE(AV, EAV)                                      \
  {                                                           \
    float v = lrelu((AV) + fmaf((EAV), wev, xrr));            \
    float p = red8(v * attv);                                 \
    if (p > m + 8.f) {                                        \
      float mn = fmaxf(m, p);                                 \
      float sc = __expf(m - mn);                              \
      den *= sc;                                              \
      acc *= sc;                                              \
      m = mn;                                                 \
    }                                                         \
    float ex = __expf(p - m);                                 \
    den += ex;                                                \
    acc = fmaf(ex, (AV), acc);                                \
  }

  int i1 = kb + 1 < ke ? kb + 1 : ke - 1;
  int2 edA = cedge[kb], edB = cedge[i1];
  float aA = xl[edA.x * 8 + lane];
  float aB = xl[edB.x * 8 + lane];
  for (int k = kb; k < ke; k += 2) {
    const int i2 = k + 2 < ke ? k + 2 : ke - 1;
    const int i3 = k + 3 < ke ? k + 3 : ke - 1;
    const int2 edC = cedge[i2], edD = cedge[i3];
    const float aC = xl[edC.x * 8 + lane];
    const float aD = xl[edD.x * 8 + lane];
    G3_EDGE(aA, __int_as_float(edA.y));
    if (k + 1 < ke) {
      G3_EDGE(aB, __int_as_float(edB.y));
    }
    aA = aC; edA = edC; aB = aD; edB = edD;
  }
#undef G3_EDGE

  hout[node * 8 + lane] = tanhf(acc / den + bias[lane]);
}

// one wave per graph: segmented mean-pool + head, no atomics.
__global__ __launch_bounds__(256) void k_poolG(const int* __restrict__ gstart,
                                               const float* __restrict__ h3,
                                               const float* __restrict__ w4,
                                               const float* __restrict__ b4,
                                               float* __restrict__ out) {
  const int lane = threadIdx.x & 63;
  const int g = blockIdx.x * 4 + (threadIdx.x >> 6);
  if (g >= NB) return;
  const int kb = gstart[g], ke = gstart[g + 1];
  const int ch = lane & 7, no = lane >> 3;
  float acc = 0.f;
  for (int n = kb + no; n < ke; n += 8)
    acc += h3[(size_t)n * 8 + ch];
  acc += __shfl_xor(acc, 8);
  acc += __shfl_xor(acc, 16);
  acc += __shfl_xor(acc, 32);
  float cnt = fmaxf((float)(ke - kb), 1.f);
  float yv = (acc / cnt) * w4[ch];
  yv = red8(yv);
  if (lane == 0) out[g] = yv + b4[0];
}

extern "C" void kernel_launch(void* const* d_in, const int* in_sizes, int n_in,
                              void* d_out, int out_size, void* d_ws, size_t ws_size,
                              hipStream_t stream) {
  const float* x   = (const float*)d_in[0];
  const int*   ei  = (const int*)d_in[1];
  const float* ea  = (const float*)d_in[2];
  const int*   bat = (const int*)d_in[3];
  const float* w0  = (const float*)d_in[4];
  const float* b0  = (const float*)d_in[5];
  const float* wl1 = (const float*)d_in[6];
  const float* wr1 = (const float*)d_in[7];
  const float* we1 = (const float*)d_in[8];
  const float* at1 = (const float*)d_in[9];
  const float* b1  = (const float*)d_in[10];
  const float* wl2 = (const float*)d_in[11];
  const float* wr2 = (const float*)d_in[12];
  const float* we2 = (const float*)d_in[13];
  const float* at2 = (const float*)d_in[14];
  const float* b2  = (const float*)d_in[15];
  const float* wl3 = (const float*)d_in[16];
  const float* wr3 = (const float*)d_in[17];
  const float* we3 = (const float*)d_in[18];
  const float* at3 = (const float*)d_in[19];
  const float* b3  = (const float*)d_in[20];
  const float* w4  = (const float*)d_in[21];
  const float* b4  = (const float*)d_in[22];
  float* out = (float*)d_out;

  char* W = (char*)d_ws;
  size_t o = 0;
  auto alloc = [&](size_t bytes) { void* p = W + o; o += (bytes + 255) & ~(size_t)255; return p; };
  int*      degi   = (int*)alloc(NN * 4);   // degi/fillc/lpa contiguous (one memset)
  int*      fillc  = (int*)alloc(NN * 4);
  float*    lpa    = (float*)alloc(NN * 4);
  int*      rowptr = (int*)alloc((NN + 1) * 4);
  int*      pre    = (int*)alloc(NN * 4);
  int*      bsum   = (int*)alloc(256 * 4);
  int*      gstart = (int*)alloc((NB + 1) * 4);
  int2*     cedge  = (int2*)alloc((size_t)NEF * 8);
  short*    Ah     = (short*)alloc((size_t)NNP * 256 * 2);
  short*    Al     = (short*)alloc((size_t)NNP * 256 * 2);
  short*    Bh     = (short*)alloc((size_t)256 * 256 * 2);
  short*    Bl     = (short*)alloc((size_t)256 * 256 * 2);
  _Float16* Xlh2   = (_Float16*)alloc((size_t)NNP * 128 * 2);
  float*    Xr2    = (float*)alloc((size_t)NNP * 128 * 4);
  float*    H2     = (float*)alloc((size_t)NN * 128 * 4);
  float*    Xl3    = (float*)alloc((size_t)NN * 8 * 4);
  float*    Xr3    = (float*)alloc((size_t)NN * 8 * 4);
  float*    H3     = (float*)alloc((size_t)NN * 8 * 4);
  (void)ws_size; (void)in_sizes; (void)n_in; (void)out_size;

  const int NBLK = cdiv(NN, 256);  // == NBLK_C

  // ---- CSR build (+ graph bounds merged into scanA) ----
  hipMemsetAsync(degi, 0, 3 * NN * 4, stream);  // degi + fillc + lpa
  k_deg<<<cdiv(NE, 256), 256, 0, stream>>>(ei, ea, degi, lpa);
  k_scanA<<<NBLK, 256, 0, stream>>>(degi, pre, bsum, lpa, bat, gstart);
  k_scan3<<<NBLK, 256, 0, stream>>>(pre, bsum, rowptr);
  k_fill<<<cdiv(NEF, 256), 256, 0, stream>>>(ei, ea, lpa, rowptr, fillc, cedge);

  // ---- layer 1 (fused transform+gather from raw x; emits bf16 hi/lo h1) ----
  k_gat1<<<NNP / 4, 256, 0, stream>>>(rowptr, cedge, x, w0, b0, wl1, wr1, we1, at1, b1, Ah, Al);

  // ---- layer 2: MFMA GEMM (BM=128, XCD-swizzled) + fp16 gather ----
  k_wsplit<<<256, 256, 0, stream>>>(wl2, wr2, Bh, Bl);
  k_gemm2<<<(NNP / 128) * 4, 256, 0, stream>>>(Ah, Al, Bh, Bl, Xlh2, Xr2);
  k_gat2<<<cdiv(NN, 4), 256, 0, stream>>>(rowptr, cedge, Xlh2, Xr2, we2, at2, b2, H2);

  // ---- layer 3 ----
  k_mm3<<<NN / 64, 256, 0, stream>>>(H2, wl3, wr3, Xl3, Xr3);
  k_gat3<<<cdiv(NN, 32), 256, 0, stream>>>(rowptr, cedge, Xl3, Xr3, we3, at3, b3, H3);

  // ---- pooling + head (segmented, no atomics) ----
  k_poolG<<<cdiv(NB, 4), 256, 0, stream>>>(gstart, H3, w4, b4, out);
}